// Round 6
// baseline (721.669 us; speedup 1.0000x reference)
//
#include <hip/hip_runtime.h>
#include <math.h>

#define HH 512
#define WW 512
#define HB 128      // band height (4 bands per plane)
#define LROW 524    // 512 + 10 halo + 2 spare floats, 16B-aligned stride
#define PADL 5
#define NF 4        // fields: mu_p, mu_t, E[p^2+t^2], E[p*t] (conv linearity;
                    // separate clamps on sigma_p/sigma_t are numerically dead
                    // for this data: window sigma^2 ~0.05 vs fp noise ~1e-7)

// R1-R5 lesson: this toolchain hard-caps 512-thread kernels at 128 VGPRs
// regardless of __launch_bounds__ ((512,4)->64, (512,2)->128, (512,1)->128),
// and the 4-field scatter-ring (44 persistent acc regs) spilled ~7 regs/row
// -> 0.9-2.5 GB scratch traffic = the entire runtime. This version keeps only
// the raw (p,t) history ring (22 regs, static indices via 11-phase unroll)
// and computes the 4 vertical sums by GATHER per output row (77 VALU ops vs
// 47 for scatter). Persistent set ~50 regs, peak ~90 -> fits 128, no spill.

// Prologue: load input row r0+S into ring slot S (S = 0..9), static indices.
#define PRO(S) {                                                           \
    const int rr = r0 + (S);                                               \
    const bool v = (rr >= 0) && (rr < HH);                                 \
    ph[(S)] = v ? P[(size_t)rr * WW + tid] : 0.f;                          \
    th[(S)] = v ? T[(size_t)rr * WW + tid] : 0.f;                          \
  }

// ROW(J): output row r = rb + J (rb a multiple of 11 -> all %11 static).
// Consume prefetched input row s=r+10 into slot (J+10)%11, prefetch s=r+11,
// gather the 4 vertical sums from the 11-slot history, then H-pass + SSIM.
#define ROW(J) if (rb + (J) < HB) {                                        \
    const int r_ = rb + (J);                                               \
    ph[((J) + 10) % 11] = pn; th[((J) + 10) % 11] = tn;                    \
    {                                                                      \
      const int rn_ = r0 + r_ + 11;                                        \
      const bool vn_ = (rn_ >= 0) && (rn_ < HH) && (r_ + 11 < 138);        \
      pn = vn_ ? P[(size_t)rn_ * WW + tid] : 0.f;                          \
      tn = vn_ ? T[(size_t)rn_ * WW + tid] : 0.f;                          \
    }                                                                      \
    float mu_p, mu_t, s2, sc;                                              \
    {                                                                      \
      const float p0 = ph[(J) % 11], t0 = th[(J) % 11];                    \
      const float up = w[0] * p0, ut = w[0] * t0;                          \
      mu_p = up; mu_t = ut;                                                \
      s2 = fmaf(up, p0, ut * t0);                                          \
      sc = up * t0;                                                        \
    }                                                                      \
    _Pragma("unroll")                                                      \
    for (int j = 1; j < 11; ++j) {                                         \
      const int sl = ((J) + j) % 11;                                       \
      const float pj = ph[sl], tj = th[sl];                                \
      const float up = w[j] * pj, ut = w[j] * tj;                          \
      mu_p += up; mu_t += ut;                                              \
      s2 = fmaf(up, pj, fmaf(ut, tj, s2));                                 \
      sc = fmaf(up, tj, sc);                                               \
    }                                                                      \
    float* Lb = &lds[r_ & 1][0][0];                                        \
    Lb[0 * LROW + PADL + tid] = mu_p;                                      \
    Lb[1 * LROW + PADL + tid] = mu_t;                                      \
    Lb[2 * LROW + PADL + tid] = s2;                                        \
    Lb[3 * LROW + PADL + tid] = sc;                                        \
    __syncthreads();                                                       \
    float hr[NF];                                                          \
    const int a2 = tid >> 1;                                               \
    _Pragma("unroll")                                                      \
    for (int f = 0; f < NF; ++f) {                                         \
      __builtin_amdgcn_sched_barrier(0);                                   \
      const float2* row2 = (const float2*)(Lb + f * LROW);                 \
      float h = 0.f;                                                       \
      _Pragma("unroll")                                                    \
      for (int m = 0; m < 6; ++m) {                                        \
        const float2 v2 = row2[a2 + m];                                    \
        h = fmaf(cx[m], v2.x, h);                                          \
        h = fmaf(cy[m], v2.y, h);                                          \
      }                                                                    \
      hr[f] = h;                                                           \
    }                                                                      \
    __builtin_amdgcn_sched_barrier(0);                                     \
    const float hmp = hr[0], hmt = hr[1];                                  \
    const float mp2 = hmp * hmp, mt2 = hmt * hmt, mct = hmp * hmt;         \
    const float ssum = fmaxf(hr[2] - mp2 - mt2, 0.f);                      \
    const float scv = hr[3] - mct;                                         \
    const float num = fmaf(2.f, mct, 1.0e-4f) * fmaf(2.f, scv, 9.0e-4f);   \
    const float den = (mp2 + mt2 + 1.0e-4f) * (ssum + 9.0e-4f);            \
    sum += num * __builtin_amdgcn_rcpf(den);                               \
  }

__global__ __launch_bounds__(512, 1)
void ssim_main(const float* __restrict__ Pg, const float* __restrict__ Tg,
               float* __restrict__ partial) {
  __shared__ __align__(16) float lds[2][NF][LROW];
  __shared__ float wsum[8];

  const int tid = threadIdx.x;            // column 0..511
  const int blk = blockIdx.x;
  const int plane = blk >> 2;
  const int band  = blk & 3;
  const int o0 = band * HB;               // first output row of band
  const int r0 = o0 - 5;                  // first input row (may be <0)
  const float* __restrict__ P = Pg + (size_t)plane * (HH * WW);
  const float* __restrict__ T = Tg + (size_t)plane * (HH * WW);

  // zero whole LDS once (halo pads must be 0; interior overwritten each row)
  for (int idx = tid; idx < 2 * NF * LROW; idx += 512)
    (&lds[0][0][0])[idx] = 0.f;
  __syncthreads();

  // Gaussian weights, computed in double then rounded to f32 (matches jnp f32)
  float w[11];
  {
    double g[11], s = 0.0;
#pragma unroll
    for (int k = 0; k < 11; ++k) {
      double c = (double)(k - 5);
      g[k] = exp(-c * c / 4.5);
      s += g[k];
    }
#pragma unroll
    for (int k = 0; k < 11; ++k)
      w[k] = __uint_as_float(__builtin_amdgcn_readfirstlane(
                 __float_as_uint((float)(g[k] / s))));
  }

  // per-lane parity-phased horizontal coefficients for aligned float2 reads:
  // even col c: taps lds[c..c+10] = {x0,y0,x1,...}; odd c: shifted by 1.
  float cx[6], cy[6];
  {
    const bool odd = (tid & 1) != 0;
#pragma unroll
    for (int m = 0; m < 6; ++m) {
      cx[m] = odd ? (m == 0 ? 0.f : w[2 * m - 1]) : w[2 * m];
      cy[m] = odd ? w[2 * m] : (m < 5 ? w[2 * m + 1] : 0.f);
    }
  }

  float sum = 0.f;

  // raw input history ring: last 11 rows of (p, t), static indexing only
  float ph[11], th[11];
  PRO(0) PRO(1) PRO(2) PRO(3) PRO(4)
  PRO(5) PRO(6) PRO(7) PRO(8) PRO(9)

  // prefetch input row s=10 (r0+10 = o0+5, always in range)
  float pn = P[(size_t)(r0 + 10) * WW + tid];
  float tn = T[(size_t)(r0 + 10) * WW + tid];

  // 128 output rows in chunks of 11 (rb multiple of 11 -> static %11 phases)
  for (int rb = 0; rb < HB; rb += 11) {
    ROW(0) ROW(1) ROW(2) ROW(3) ROW(4) ROW(5)
    ROW(6) ROW(7) ROW(8) ROW(9) ROW(10)
  }

  // block reduction of ssim partial sum
#pragma unroll
  for (int off = 32; off > 0; off >>= 1) sum += __shfl_down(sum, off, 64);
  if ((tid & 63) == 0) wsum[tid >> 6] = sum;
  __syncthreads();
  if (tid == 0) {
    float s = 0.f;
#pragma unroll
    for (int k2 = 0; k2 < 8; ++k2) s += wsum[k2];
    partial[blk] = s;
  }
}

__global__ void ssim_fin(const float* __restrict__ partial,
                         float* __restrict__ out, int n) {
  __shared__ double ws[4];
  double s = 0.0;
  for (int idx = threadIdx.x; idx < n; idx += 256) s += (double)partial[idx];
#pragma unroll
  for (int off = 32; off > 0; off >>= 1) s += __shfl_down(s, off, 64);
  if ((threadIdx.x & 63) == 0) ws[threadIdx.x >> 6] = s;
  __syncthreads();
  if (threadIdx.x == 0) {
    double tt = ws[0] + ws[1] + ws[2] + ws[3];
    out[0] = (float)(1.0 - tt / 32505856.0);
  }
}

extern "C" void kernel_launch(void* const* d_in, const int* in_sizes, int n_in,
                              void* d_out, int out_size, void* d_ws, size_t ws_size,
                              hipStream_t stream) {
  const float* pred = (const float*)d_in[0];
  const float* tgt  = (const float*)d_in[1];
  float* out        = (float*)d_out;
  float* partial    = (float*)d_ws;   // 496 floats of scratch

  ssim_main<<<dim3(496), dim3(512), 0, stream>>>(pred, tgt, partial);
  ssim_fin<<<dim3(1), dim3(256), 0, stream>>>(partial, out, 496);
}

// Round 7
// 191.026 us; speedup vs baseline: 3.7779x; 3.7779x over previous
//
#include <hip/hip_runtime.h>
#include <math.h>

#define HH 512
#define WW 512
#define HB 128      // band height (4 bands per plane)
#define LROW 524    // 5 left pad + 512 + 7 right pad, 16B-aligned stride
#define PADL 5
#define NF 4        // fields: mu_p, mu_t, E[p^2+t^2], E[p*t] (conv linearity;
                    // separate clamps on sigma_p/sigma_t are numerically dead
                    // for this data: window sigma^2 ~0.05 vs fp noise ~1e-7)
#define KR 4        // output rows per group

// R1-R6 lesson: any design with a persistent per-thread row-state ring
// (acc[4][11]=44 or ph/th[11]=22 regs) spills under the 128-VGPR cap this
// toolchain pins on 512-thread kernels, costing 0.9-1.3 GB/dispatch of
// scratch writes (= the entire runtime; warm dispatches show FETCH~0 and
// WRITE=1.3GB). This version has NO persistent row state: each 4-row group
// streams its 14 input rows from global (10/14 L1/L2-hot from the previous
// group) into 16 accumulators, stages to LDS, then runs the validated
// parity-float2 H-pass. Peak live ~80 regs, ~45 below the cap.

__global__ __launch_bounds__(512, 1)
void ssim_main(const float* __restrict__ Pg, const float* __restrict__ Tg,
               float* __restrict__ partial) {
  __shared__ __align__(16) float S[KR][NF][LROW];  // single-buffered group tile
  __shared__ float wsum[8];

  const int tid = threadIdx.x;            // column 0..511
  const int blk = blockIdx.x;
  const int plane = blk >> 2;
  const int band  = blk & 3;
  const int o0 = band * HB;               // first output row of band
  const float* __restrict__ P = Pg + (size_t)plane * (HH * WW);
  const float* __restrict__ T = Tg + (size_t)plane * (HH * WW);

  // zero LDS once: halo pads must be 0; interior overwritten every group
  for (int idx = tid; idx < KR * NF * LROW; idx += 512)
    (&S[0][0][0])[idx] = 0.f;

  // Gaussian weights, computed in double then rounded to f32 (matches jnp f32)
  float w[11];
  {
    double g[11], s = 0.0;
#pragma unroll
    for (int k = 0; k < 11; ++k) {
      double c = (double)(k - 5);
      g[k] = exp(-c * c / 4.5);
      s += g[k];
    }
#pragma unroll
    for (int k = 0; k < 11; ++k)
      w[k] = __uint_as_float(__builtin_amdgcn_readfirstlane(
                 __float_as_uint((float)(g[k] / s))));
  }

  // per-lane parity-phased horizontal coefficients for aligned float2 reads:
  // even col c: taps lds[c..c+10] = {x0,y0,x1,...}; odd c: shifted by 1.
  // (validated exact in R1-R6, absmax 0.0)
  float cx[6], cy[6];
  {
    const bool odd = (tid & 1) != 0;
#pragma unroll
    for (int m = 0; m < 6; ++m) {
      cx[m] = odd ? (m == 0 ? 0.f : w[2 * m - 1]) : w[2 * m];
      cy[m] = odd ? w[2 * m] : (m < 5 ? w[2 * m + 1] : 0.f);
    }
  }

  float sum = 0.f;
  const int a2 = tid >> 1;

  for (int g = 0; g < HB; g += KR) {      // 32 groups of 4 output rows
    // ---- vertical pass: stream 14 input rows, 16 accumulators ----
    float mp[KR], mt[KR], s2[KR], sc[KR];
#pragma unroll
    for (int j = 0; j < KR; ++j) { mp[j] = 0.f; mt[j] = 0.f; s2[j] = 0.f; sc[j] = 0.f; }
    const int rbase = o0 + g - 5;         // input row of ri=0 (may be <0)
#pragma unroll
    for (int ri = 0; ri < KR + 10; ++ri) {
      const int r_in = rbase + ri;
      const bool v = (r_in >= 0) && (r_in < HH);
      const float p = v ? P[(size_t)r_in * WW + tid] : 0.f;
      const float t = v ? T[(size_t)r_in * WW + tid] : 0.f;
#pragma unroll
      for (int j = 0; j < KR; ++j) {
        if (ri - j >= 0 && ri - j <= 10) {     // compile-time per (ri,j)
          const float wk = w[ri - j];
          const float up = wk * p, ut = wk * t;
          mp[j] += up; mt[j] += ut;
          s2[j] = fmaf(up, p, fmaf(ut, t, s2[j]));
          sc[j] = fmaf(up, t, sc[j]);
        }
      }
    }

    // ---- stage group tile (single buffer: barrier, write, barrier) ----
    __syncthreads();                      // prior group's readers are done
#pragma unroll
    for (int j = 0; j < KR; ++j) {
      S[j][0][PADL + tid] = mp[j];
      S[j][1][PADL + tid] = mt[j];
      S[j][2][PADL + tid] = s2[j];
      S[j][3][PADL + tid] = sc[j];
    }
    __syncthreads();

    // ---- horizontal pass + SSIM, row by row ----
#pragma unroll
    for (int j = 0; j < KR; ++j) {
      __builtin_amdgcn_sched_barrier(0);  // cap in-flight LDS loads per row
      float hr[NF];
#pragma unroll
      for (int f = 0; f < NF; ++f) {
        const float2* row2 = (const float2*)(&S[j][f][0]);
        float h = 0.f;
#pragma unroll
        for (int m = 0; m < 6; ++m) {
          const float2 v2 = row2[a2 + m];
          h = fmaf(cx[m], v2.x, h);
          h = fmaf(cy[m], v2.y, h);
        }
        hr[f] = h;
      }
      const float hmp = hr[0], hmt = hr[1];
      const float mp2 = hmp * hmp, mt2 = hmt * hmt, mct = hmp * hmt;
      const float ssum = fmaxf(hr[2] - mp2 - mt2, 0.f);
      const float scv = hr[3] - mct;
      const float num = fmaf(2.f, mct, 1.0e-4f) * fmaf(2.f, scv, 9.0e-4f);
      const float den = (mp2 + mt2 + 1.0e-4f) * (ssum + 9.0e-4f);
      sum += num * __builtin_amdgcn_rcpf(den);
    }
  }

  // block reduction of ssim partial sum
#pragma unroll
  for (int off = 32; off > 0; off >>= 1) sum += __shfl_down(sum, off, 64);
  if ((tid & 63) == 0) wsum[tid >> 6] = sum;
  __syncthreads();
  if (tid == 0) {
    float s = 0.f;
#pragma unroll
    for (int k2 = 0; k2 < 8; ++k2) s += wsum[k2];
    partial[blk] = s;
  }
}

__global__ void ssim_fin(const float* __restrict__ partial,
                         float* __restrict__ out, int n) {
  __shared__ double ws[4];
  double s = 0.0;
  for (int idx = threadIdx.x; idx < n; idx += 256) s += (double)partial[idx];
#pragma unroll
  for (int off = 32; off > 0; off >>= 1) s += __shfl_down(s, off, 64);
  if ((threadIdx.x & 63) == 0) ws[threadIdx.x >> 6] = s;
  __syncthreads();
  if (threadIdx.x == 0) {
    double tt = ws[0] + ws[1] + ws[2] + ws[3];
    out[0] = (float)(1.0 - tt / 32505856.0);
  }
}

extern "C" void kernel_launch(void* const* d_in, const int* in_sizes, int n_in,
                              void* d_out, int out_size, void* d_ws, size_t ws_size,
                              hipStream_t stream) {
  const float* pred = (const float*)d_in[0];
  const float* tgt  = (const float*)d_in[1];
  float* out        = (float*)d_out;
  float* partial    = (float*)d_ws;   // 496 floats of scratch

  ssim_main<<<dim3(496), dim3(512), 0, stream>>>(pred, tgt, partial);
  ssim_fin<<<dim3(1), dim3(256), 0, stream>>>(partial, out, 496);
}

// Round 8
// 171.796 us; speedup vs baseline: 4.2007x; 1.1119x over previous
//
#include <hip/hip_runtime.h>
#include <math.h>

#define HH 512
#define WW 512
#define HB 64       // band height (8 bands per plane -> grid 992, ~3.9 blk/CU)
#define LROW 524    // 5 left pad + 512 + 7 right pad, 16B-aligned stride
#define PADL 5
#define NF 4        // fields: mu_p, mu_t, E[p^2+t^2], E[p*t] (conv linearity;
                    // separate clamps on sigma_p/sigma_t are numerically dead
                    // for this data: window sigma^2 ~0.05 vs fp noise ~1e-7)
#define KR 4        // output rows per group (16 accumulators, proven no-spill)

// R7 established the winning structure: NO persistent per-thread row state
// (every ring-buffer design spilled under the 128-VGPR cap; R7 got VGPR=64,
// WRITE_SIZE ~0, 191 us). R8 adds:
//  - HB 128->64: grid 496->992 blocks (~3.9/CU), doubling occupancy (R7 was
//    grid-capped at 37%; 32% of VALU cycles were idle).
//  - q2/q3 per-row precompute: vertical tap = 4 FMAs instead of 7 ops
//    (77->62 ops/pt on the vertical pass).

__global__ __launch_bounds__(512, 1)
void ssim_main(const float* __restrict__ Pg, const float* __restrict__ Tg,
               float* __restrict__ partial) {
  __shared__ __align__(16) float S[KR][NF][LROW];  // single-buffered group tile
  __shared__ float wsum[8];

  const int tid = threadIdx.x;            // column 0..511
  const int blk = blockIdx.x;
  const int plane = blk >> 3;
  const int band  = blk & 7;
  const int o0 = band * HB;               // first output row of band
  const float* __restrict__ P = Pg + (size_t)plane * (HH * WW);
  const float* __restrict__ T = Tg + (size_t)plane * (HH * WW);

  // zero LDS once: halo pads must be 0; interior overwritten every group
  for (int idx = tid; idx < KR * NF * LROW; idx += 512)
    (&S[0][0][0])[idx] = 0.f;

  // Gaussian weights, computed in double then rounded to f32 (matches jnp f32)
  float w[11];
  {
    double g[11], s = 0.0;
#pragma unroll
    for (int k = 0; k < 11; ++k) {
      double c = (double)(k - 5);
      g[k] = exp(-c * c / 4.5);
      s += g[k];
    }
#pragma unroll
    for (int k = 0; k < 11; ++k)
      w[k] = __uint_as_float(__builtin_amdgcn_readfirstlane(
                 __float_as_uint((float)(g[k] / s))));
  }

  // per-lane parity-phased horizontal coefficients for aligned float2 reads:
  // even col c: taps lds[c..c+10] = {x0,y0,x1,...}; odd c: shifted by 1.
  // (validated exact in R1-R7, absmax 0.0)
  float cx[6], cy[6];
  {
    const bool odd = (tid & 1) != 0;
#pragma unroll
    for (int m = 0; m < 6; ++m) {
      cx[m] = odd ? (m == 0 ? 0.f : w[2 * m - 1]) : w[2 * m];
      cy[m] = odd ? w[2 * m] : (m < 5 ? w[2 * m + 1] : 0.f);
    }
  }

  float sum = 0.f;
  const int a2 = tid >> 1;

  for (int g = 0; g < HB; g += KR) {      // 16 groups of 4 output rows
    // ---- vertical pass: stream 14 input rows, 16 accumulators ----
    float mp[KR], mt[KR], s2[KR], sc[KR];
#pragma unroll
    for (int j = 0; j < KR; ++j) { mp[j] = 0.f; mt[j] = 0.f; s2[j] = 0.f; sc[j] = 0.f; }
    const int rbase = o0 + g - 5;         // input row of ri=0 (may be <0)
#pragma unroll
    for (int ri = 0; ri < KR + 10; ++ri) {
      const int r_in = rbase + ri;
      const bool v = (r_in >= 0) && (r_in < HH);
      const float p = v ? P[(size_t)r_in * WW + tid] : 0.f;
      const float t = v ? T[(size_t)r_in * WW + tid] : 0.f;
      const float q2 = fmaf(t, t, p * p);      // per-row precompute:
      const float q3 = p * t;                  // tap = 4 straight FMAs
#pragma unroll
      for (int j = 0; j < KR; ++j) {
        if (ri - j >= 0 && ri - j <= 10) {     // compile-time per (ri,j)
          const float wk = w[ri - j];
          mp[j] = fmaf(wk, p,  mp[j]);
          mt[j] = fmaf(wk, t,  mt[j]);
          s2[j] = fmaf(wk, q2, s2[j]);
          sc[j] = fmaf(wk, q3, sc[j]);
        }
      }
    }

    // ---- stage group tile (single buffer: barrier, write, barrier) ----
    __syncthreads();                      // prior group's readers are done
#pragma unroll
    for (int j = 0; j < KR; ++j) {
      S[j][0][PADL + tid] = mp[j];
      S[j][1][PADL + tid] = mt[j];
      S[j][2][PADL + tid] = s2[j];
      S[j][3][PADL + tid] = sc[j];
    }
    __syncthreads();

    // ---- horizontal pass + SSIM, row by row ----
#pragma unroll
    for (int j = 0; j < KR; ++j) {
      __builtin_amdgcn_sched_barrier(0);  // cap in-flight LDS loads per row
      float hr[NF];
#pragma unroll
      for (int f = 0; f < NF; ++f) {
        const float2* row2 = (const float2*)(&S[j][f][0]);
        float h = 0.f;
#pragma unroll
        for (int m = 0; m < 6; ++m) {
          const float2 v2 = row2[a2 + m];
          h = fmaf(cx[m], v2.x, h);
          h = fmaf(cy[m], v2.y, h);
        }
        hr[f] = h;
      }
      const float hmp = hr[0], hmt = hr[1];
      const float mp2 = hmp * hmp, mt2 = hmt * hmt, mct = hmp * hmt;
      const float ssum = fmaxf(hr[2] - mp2 - mt2, 0.f);
      const float scv = hr[3] - mct;
      const float num = fmaf(2.f, mct, 1.0e-4f) * fmaf(2.f, scv, 9.0e-4f);
      const float den = (mp2 + mt2 + 1.0e-4f) * (ssum + 9.0e-4f);
      sum += num * __builtin_amdgcn_rcpf(den);
    }
  }

  // block reduction of ssim partial sum
#pragma unroll
  for (int off = 32; off > 0; off >>= 1) sum += __shfl_down(sum, off, 64);
  if ((tid & 63) == 0) wsum[tid >> 6] = sum;
  __syncthreads();
  if (tid == 0) {
    float s = 0.f;
#pragma unroll
    for (int k2 = 0; k2 < 8; ++k2) s += wsum[k2];
    partial[blk] = s;
  }
}

__global__ void ssim_fin(const float* __restrict__ partial,
                         float* __restrict__ out, int n) {
  __shared__ double ws[4];
  double s = 0.0;
  for (int idx = threadIdx.x; idx < n; idx += 256) s += (double)partial[idx];
#pragma unroll
  for (int off = 32; off > 0; off >>= 1) s += __shfl_down(s, off, 64);
  if ((threadIdx.x & 63) == 0) ws[threadIdx.x >> 6] = s;
  __syncthreads();
  if (threadIdx.x == 0) {
    double tt = ws[0] + ws[1] + ws[2] + ws[3];
    out[0] = (float)(1.0 - tt / 32505856.0);
  }
}

extern "C" void kernel_launch(void* const* d_in, const int* in_sizes, int n_in,
                              void* d_out, int out_size, void* d_ws, size_t ws_size,
                              hipStream_t stream) {
  const float* pred = (const float*)d_in[0];
  const float* tgt  = (const float*)d_in[1];
  float* out        = (float*)d_out;
  float* partial    = (float*)d_ws;   // 992 floats of scratch

  ssim_main<<<dim3(992), dim3(512), 0, stream>>>(pred, tgt, partial);
  ssim_fin<<<dim3(1), dim3(256), 0, stream>>>(partial, out, 992);
}

// Round 9
// 122.720 us; speedup vs baseline: 5.8806x; 1.3999x over previous
//
#include <hip/hip_runtime.h>
#include <math.h>

#define HH 512
#define WW 512
#define HB 64       // band height (8 bands per plane -> grid 992)
#define NR4 528     // float4 elems per row: 8 left pad + 512 + 8 right pad
#define PADL 8      // 8-aligned pad so stride-1 writes stay in one XOR block
#define KR 4        // output rows per group (16 accumulators, proven no-spill)

// R8 post-mortem: kernel was LDS-pipe-bound (24 ds_read_b64 + 4 ds_write_b32
// per point ~= 140us of LDS cycles out of 172us total; VALU need only ~48us).
// R9 cuts LDS traffic ~4x:
//  - field-interleaved float4 LDS: one b128 read = all 4 fields of a column
//  - 4-column coarsening: 14 b128 reads per 4 output points (tap reuse)
//  - XOR swizzle u^((u>>3)&7): stride-4 reads AND stride-1 writes both
//    conflict-free (each aligned 8-lane group hits 8 distinct bank-groups)
// Keeps R7/R8's proven no-persistent-state vertical pass (VGPR 64, no spill).

__device__ __forceinline__ int swz(int u) { return u ^ ((u >> 3) & 7); }

__global__ __launch_bounds__(512, 1)
void ssim_main(const float* __restrict__ Pg, const float* __restrict__ Tg,
               float* __restrict__ partial) {
  __shared__ __align__(16) float4 S4[KR][NR4];
  __shared__ float wsum[8];

  const int tid = threadIdx.x;            // vertical pass: column 0..511
  const int blk = blockIdx.x;
  const int plane = blk >> 3;
  const int band  = blk & 7;
  const int o0 = band * HB;               // first output row of band
  const float* __restrict__ P = Pg + (size_t)plane * (HH * WW);
  const float* __restrict__ T = Tg + (size_t)plane * (HH * WW);

  // zero LDS once: halo pads (u<8, u>=520) must be 0 and are never rewritten;
  // interior u in [8,520) is fully overwritten every group (swz is a
  // bijection within each aligned 8-block).
  {
    float4* base = &S4[0][0];
    const float4 z = make_float4(0.f, 0.f, 0.f, 0.f);
    for (int idx = tid; idx < KR * NR4; idx += 512) base[idx] = z;
  }

  // Gaussian weights, computed in double then rounded to f32 (matches jnp f32)
  float w[11];
  {
    double g[11], s = 0.0;
#pragma unroll
    for (int k = 0; k < 11; ++k) {
      double c = (double)(k - 5);
      g[k] = exp(-c * c / 4.5);
      s += g[k];
    }
#pragma unroll
    for (int k = 0; k < 11; ++k)
      w[k] = __uint_as_float(__builtin_amdgcn_readfirstlane(
                 __float_as_uint((float)(g[k] / s))));
  }

  float sum = 0.f;
  const int jr = tid >> 7;                // H-pass: row within group (0..3)
  const int q  = tid & 127;               // H-pass: 4-col block (cols 4q..4q+3)

  for (int g = 0; g < HB; g += KR) {      // 16 groups of 4 output rows
    // ---- vertical pass: stream 14 input rows, 16 accumulators ----
    float mp[KR], mt[KR], s2[KR], sc[KR];
#pragma unroll
    for (int j = 0; j < KR; ++j) { mp[j] = 0.f; mt[j] = 0.f; s2[j] = 0.f; sc[j] = 0.f; }
    const int rbase = o0 + g - 5;         // input row of ri=0 (may be <0)
#pragma unroll
    for (int ri = 0; ri < KR + 10; ++ri) {
      const int r_in = rbase + ri;
      const bool v = (r_in >= 0) && (r_in < HH);
      const float p = v ? P[(size_t)r_in * WW + tid] : 0.f;
      const float t = v ? T[(size_t)r_in * WW + tid] : 0.f;
      const float q2 = fmaf(t, t, p * p);
      const float q3 = p * t;
#pragma unroll
      for (int j = 0; j < KR; ++j) {
        if (ri - j >= 0 && ri - j <= 10) {     // compile-time per (ri,j)
          const float wk = w[ri - j];
          mp[j] = fmaf(wk, p,  mp[j]);
          mt[j] = fmaf(wk, t,  mt[j]);
          s2[j] = fmaf(wk, q2, s2[j]);
          sc[j] = fmaf(wk, q3, sc[j]);
        }
      }
    }

    // ---- stage group tile (field-packed float4, swizzled) ----
    __syncthreads();                      // prior group's readers are done
#pragma unroll
    for (int j = 0; j < KR; ++j)
      S4[j][swz(PADL + tid)] = make_float4(mp[j], mt[j], s2[j], sc[j]);
    __syncthreads();

    // ---- horizontal pass + SSIM: 4 columns per thread, 14 taps ----
    float hp[4], ht[4], h2[4], hc[4];
#pragma unroll
    for (int m = 0; m < 4; ++m) { hp[m] = 0.f; ht[m] = 0.f; h2[m] = 0.f; hc[m] = 0.f; }
#pragma unroll
    for (int k = 0; k < 14; ++k) {
      // tap column = 4q - 5 + k  ->  u = PADL + 4q - 5 + k = 4q + 3 + k
      const float4 v4 = S4[jr][swz(4 * q + 3 + k)];
#pragma unroll
      for (int m = 0; m < 4; ++m) {
        if (k - m >= 0 && k - m <= 10) {       // compile-time per (k,m)
          const float wk = w[k - m];
          hp[m] = fmaf(wk, v4.x, hp[m]);
          ht[m] = fmaf(wk, v4.y, ht[m]);
          h2[m] = fmaf(wk, v4.z, h2[m]);
          hc[m] = fmaf(wk, v4.w, hc[m]);
        }
      }
    }
#pragma unroll
    for (int m = 0; m < 4; ++m) {
      const float hmp = hp[m], hmt = ht[m];
      const float mp2 = hmp * hmp, mt2 = hmt * hmt, mct = hmp * hmt;
      const float ssum = fmaxf(h2[m] - mp2 - mt2, 0.f);
      const float scv = hc[m] - mct;
      const float num = fmaf(2.f, mct, 1.0e-4f) * fmaf(2.f, scv, 9.0e-4f);
      const float den = (mp2 + mt2 + 1.0e-4f) * (ssum + 9.0e-4f);
      sum += num * __builtin_amdgcn_rcpf(den);
    }
  }

  // block reduction of ssim partial sum
#pragma unroll
  for (int off = 32; off > 0; off >>= 1) sum += __shfl_down(sum, off, 64);
  if ((tid & 63) == 0) wsum[tid >> 6] = sum;
  __syncthreads();
  if (tid == 0) {
    float s = 0.f;
#pragma unroll
    for (int k2 = 0; k2 < 8; ++k2) s += wsum[k2];
    partial[blk] = s;
  }
}

__global__ void ssim_fin(const float* __restrict__ partial,
                         float* __restrict__ out, int n) {
  __shared__ double ws[4];
  double s = 0.0;
  for (int idx = threadIdx.x; idx < n; idx += 256) s += (double)partial[idx];
#pragma unroll
  for (int off = 32; off > 0; off >>= 1) s += __shfl_down(s, off, 64);
  if ((threadIdx.x & 63) == 0) ws[threadIdx.x >> 6] = s;
  __syncthreads();
  if (threadIdx.x == 0) {
    double tt = ws[0] + ws[1] + ws[2] + ws[3];
    out[0] = (float)(1.0 - tt / 32505856.0);
  }
}

extern "C" void kernel_launch(void* const* d_in, const int* in_sizes, int n_in,
                              void* d_out, int out_size, void* d_ws, size_t ws_size,
                              hipStream_t stream) {
  const float* pred = (const float*)d_in[0];
  const float* tgt  = (const float*)d_in[1];
  float* out        = (float*)d_out;
  float* partial    = (float*)d_ws;   // 992 floats of scratch

  ssim_main<<<dim3(992), dim3(512), 0, stream>>>(pred, tgt, partial);
  ssim_fin<<<dim3(1), dim3(256), 0, stream>>>(partial, out, 992);
}